// Round 1
// baseline (10840.814 us; speedup 1.0000x reference)
//
#include <hip/hip_runtime.h>
#include <math.h>

#define B_ 512
#define S_ 256
#define D_ 256
#define NLOC 50000
#define KX 448      // D + TEMP
#define KC 704      // KX + D
#define G4 1024
#define NEGV -1000000000.0f

__device__ __forceinline__ float sigmoidf_(float x){ return 1.0f/(1.0f+expf(-x)); }
__device__ __forceinline__ float geluf_(float x){ return 0.5f*x*(1.0f+erff(x*0.70710678118654752f)); }

// ---- init: zero h0, c, flag ----
__global__ void k_init(float* h, float* c, int* flag){
  int i = blockIdx.x*256 + threadIdx.x;
  if (i < B_*D_){ h[i]=0.f; c[i]=0.f; }
  if (i==0) *flag = 0;
}

// ---- detect mask layout: any nonzero odd byte in first B*S bytes => uint8 ----
__global__ void k_detect(const unsigned char* m, int* flag){
  int i = blockIdx.x*256 + threadIdx.x;
  if ((i & 1) && i < B_*S_ && m[i]) atomicOr(flag, 1);
}

// ---- seq_lens[b] = count(mask row) - 1 ----
__global__ void k_seqlen(const void* mp, const int* flag, int* slens){
  int b = blockIdx.x*256 + threadIdx.x;
  if (b >= B_) return;
  int cnt = 0;
  if (*flag){
    const unsigned char* m = (const unsigned char*)mp;
    for (int s=0;s<S_;s++) cnt += (m[b*S_+s] != 0);
  } else {
    const int* m = (const int*)mp;
    for (int s=0;s<S_;s++) cnt += (m[b*S_+s] != 0);
  }
  slens[b] = cnt - 1;
}

// ---- build X = [loc_emb | user_emb | hour_emb | wd_emb], (B*S, 448) ----
__global__ void k_buildx(const int* loc, const int* usr, const int* wdy, const int* sm,
                         const float* loct, const float* usert, const float* hourt,
                         const float* wdt, float* X){
  int i = blockIdx.x*256 + threadIdx.x;           // float4 index
  if (i >= B_*S_*112) return;
  int row = i/112, c4 = i%112;
  int col = c4*4;
  float4 v;
  if (col < 256){
    int l = loc[row];
    v = *(const float4*)(loct + (size_t)l*256 + col);
  } else if (col < 320){
    int u = usr[row];
    v = *(const float4*)(usert + (size_t)u*64 + (col-256));
  } else if (col < 384){
    int s = sm[row];
    int hh = s/60; if (hh>24) hh=24; if (hh<0) hh=0;
    v = *(const float4*)(hourt + (size_t)hh*64 + (col-320));
  } else {
    int wv = wdy[row];
    v = *(const float4*)(wdt + (size_t)wv*64 + (col-384));
  }
  *(float4*)(X + (size_t)row*KX + col) = v;
}

// ---- build Wc = [W_ih | W_hh] (1024 x 704), btot = b_ih + b_hh ----
__global__ void k_buildw(const float* wih, const float* whh, const float* bih,
                         const float* bhh, float* Wc, float* btot){
  int i = blockIdx.x*256 + threadIdx.x;
  if (i < G4*KC){
    int g = i/KC, k = i%KC;
    Wc[i] = (k < KX) ? wih[(size_t)g*KX + k] : whh[(size_t)g*D_ + (k-KX)];
  }
  if (i < G4) btot[i] = bih[i] + bhh[i];
}

// ---- one LSTM step, fused dual-matmul + cell update ----
// grid (32,8): bx -> 16 batch rows, by -> 32 hidden dims; 256 threads
__global__ __launch_bounds__(256) void k_lstm(int t, const float* __restrict__ X,
    const float* __restrict__ Wc, const float* __restrict__ btot,
    const float* __restrict__ hin, float* __restrict__ hout,
    float* __restrict__ c, float* __restrict__ ctx, const int* __restrict__ slens){
  __shared__ float Ws[128][33];
  __shared__ float Xs[16][33];
  int tid = threadIdx.x;
  int dl = tid & 31, grp = tid >> 5;
  int b0 = blockIdx.x*16, d0 = blockIdx.y*32;
  float acc[4][2];
  #pragma unroll
  for (int g=0; g<4; g++){
    float bv = btot[g*D_ + d0 + dl];
    acc[g][0] = bv; acc[g][1] = bv;
  }
  for (int kt=0; kt<22; kt++){
    int k0 = kt*32;
    #pragma unroll
    for (int r=0; r<16; r++){
      int rowl = grp + 8*r;                 // 0..127
      int gate = rowl >> 5, dr = rowl & 31;
      Ws[rowl][dl] = Wc[(size_t)(gate*D_ + d0 + dr)*KC + k0 + dl];
    }
    #pragma unroll
    for (int r=0; r<2; r++){
      int i = tid + 256*r;                  // 0..511
      int bl = i >> 5, colk = i & 31;
      int k = k0 + colk;
      float v = (k < KX) ? X[((size_t)(b0+bl)*S_ + t)*KX + k]
                         : hin[(size_t)(b0+bl)*D_ + (k-KX)];
      Xs[bl][colk] = v;
    }
    __syncthreads();
    int bl0 = grp*2;
    #pragma unroll
    for (int kk=0; kk<32; kk++){
      float x0 = Xs[bl0][kk], x1 = Xs[bl0+1][kk];
      #pragma unroll
      for (int g=0; g<4; g++){
        float w = Ws[g*32+dl][kk];
        acc[g][0] += w*x0; acc[g][1] += w*x1;
      }
    }
    __syncthreads();
  }
  #pragma unroll
  for (int bi=0; bi<2; bi++){
    int b = b0 + grp*2 + bi;
    int d = d0 + dl;
    float iv = acc[0][bi], fv = acc[1][bi], gv = acc[2][bi], ov = acc[3][bi];
    float cold = c[(size_t)b*D_ + d];
    float cn = sigmoidf_(fv)*cold + sigmoidf_(iv)*tanhf(gv);
    float hn = sigmoidf_(ov)*tanhf(cn);
    c[(size_t)b*D_ + d] = cn;
    hout[(size_t)b*D_ + d] = hn;
    if (t == slens[b]) ctx[(size_t)b*D_ + d] = hn;
  }
}

// ---- newhid = gelu(ctx @ np_W1^T + np_b1); mix = sigmoid(ctx . mx_W + mx_b)*0.9+0.05 ----
__global__ void k_post1(const float* __restrict__ ctx, const float* __restrict__ W1,
                        const float* __restrict__ b1, const float* __restrict__ mxW,
                        const float* __restrict__ mxb, float* newhid, float* mixv){
  __shared__ float cs[256];
  __shared__ float red[256];
  int b = blockIdx.x, tid = threadIdx.x;
  cs[tid] = ctx[(size_t)b*D_ + tid];
  __syncthreads();
  float a = b1[tid];
  const float* wr = W1 + (size_t)tid*D_;
  for (int k=0; k<D_; k++) a += cs[k]*wr[k];
  newhid[(size_t)b*D_ + tid] = geluf_(a);
  red[tid] = cs[tid]*mxW[tid];
  __syncthreads();
  for (int s=128; s>0; s>>=1){ if (tid<s) red[tid]+=red[tid+s]; __syncthreads(); }
  if (tid==0) mixv[b] = sigmoidf_(red[0]+mxb[0])*0.9f + 0.05f;
}

// ---- recent-location scores + dedup/keep ----
__global__ void k_recent(const int* __restrict__ loc, const int* __restrict__ sm,
                         const int* __restrict__ slens, const float* __restrict__ loct,
                         const float* __restrict__ W1, const float* __restrict__ b1,
                         const float* __restrict__ W2, const float* __restrict__ b2,
                         float* scores, int* rlocs, int* keep){
  __shared__ int rl[5], vs[5];
  __shared__ float td[5];
  __shared__ float red[128];
  int b = blockIdx.x, tid = threadIdx.x;
  int sl = slens[b];
  if (tid < 5){
    int idx = sl - tid;
    int v = idx >= 0;
    int ic = v ? idx : 0;
    rl[tid] = loc[b*S_ + ic];
    vs[tid] = v;
    int cur = sm[b*S_ + sl];
    td[tid] = (float)(cur - sm[b*S_ + ic]) * (1.0f/1440.0f);
  }
  __syncthreads();
  for (int j=0; j<5; j++){
    const float* lrow = loct + (size_t)rl[j]*D_;
    const float* wr = W1 + (size_t)tid*258;
    float a = b1[tid];
    for (int k=0; k<D_; k++) a += lrow[k]*wr[k];
    a += td[j]*wr[256] + (float)j*wr[257];
    red[tid] = geluf_(a)*W2[tid];
    __syncthreads();
    for (int s=64; s>0; s>>=1){ if (tid<s) red[tid]+=red[tid+s]; __syncthreads(); }
    if (tid==0) scores[b*5+j] = red[0] + b2[0];
    __syncthreads();
  }
  if (tid==0){
    for (int j=0; j<5; j++){
      int dup = 0;
      for (int k=0; k<j; k++) dup |= (rl[j]==rl[k]) && vs[k];
      keep[b*5+j] = vs[j] && !dup;
      rlocs[b*5+j] = rl[j];
    }
  }
}

// ---- big fused head: out[b,l] = mix*NEG + (1-mix)*(newhid[b].np_W2[l] + np_b2[l]) ----
// grid (782, 32): 64 locs x 16 batch per block, 256 threads
__global__ __launch_bounds__(256) void k_final(const float* __restrict__ newhid,
    const float* __restrict__ W2, const float* __restrict__ b2,
    const float* __restrict__ mixv, float* __restrict__ out){
  __shared__ float Hs[16][256];
  __shared__ float Wl[64][65];
  int tid = threadIdx.x;
  int l0 = blockIdx.x*64, b0 = blockIdx.y*16;
  int ll = tid & 63, bq = tid >> 6;
  #pragma unroll
  for (int r=0; r<16; r++) Hs[r][tid] = newhid[(size_t)(b0+r)*D_ + tid];
  float acc[4] = {0.f,0.f,0.f,0.f};
  for (int kt=0; kt<4; kt++){
    int k0 = kt*64;
    __syncthreads();
    #pragma unroll
    for (int r=0; r<4; r++){
      int row = 4*r + bq;
      int l = l0 + row;
      Wl[row][ll] = (l < NLOC) ? W2[(size_t)l*D_ + k0 + ll] : 0.f;
    }
    __syncthreads();
    #pragma unroll
    for (int kk=0; kk<64; kk++){
      float wv = Wl[ll][kk];
      #pragma unroll
      for (int bi=0; bi<4; bi++) acc[bi] += wv * Hs[bq*4+bi][k0+kk];
    }
  }
  int l = l0 + ll;
  if (l < NLOC){
    float bias = b2[l];
    #pragma unroll
    for (int bi=0; bi<4; bi++){
      int b = b0 + bq*4 + bi;
      float mx = mixv[b];
      out[(size_t)b*NLOC + l] = mx*NEGV + (1.0f-mx)*(acc[bi] + bias);
    }
  }
}

// ---- overwrite kept recent locations: out[b,rl] = mix*score + (1-mix)*nl(rl) ----
__global__ void k_scatter(const float* __restrict__ newhid, const float* __restrict__ W2,
                          const float* __restrict__ b2, const float* __restrict__ mixv,
                          const float* __restrict__ scores, const int* __restrict__ rlocs,
                          const int* __restrict__ keep, float* out){
  int b = blockIdx.x, lane = threadIdx.x;
  float mx = mixv[b];
  for (int j=0; j<5; j++){
    if (!keep[b*5+j]) continue;
    int rl = rlocs[b*5+j];
    const float* wr = W2 + (size_t)rl*D_;
    const float* hr = newhid + (size_t)b*D_;
    float a = 0.f;
    #pragma unroll
    for (int q=0; q<4; q++){ int k = lane + 64*q; a += hr[k]*wr[k]; }
    #pragma unroll
    for (int off=32; off>0; off>>=1) a += __shfl_xor(a, off, 64);
    if (lane==0)
      out[(size_t)b*NLOC + rl] = mx*scores[b*5+j] + (1.0f-mx)*(a + b2[rl]);
  }
}

extern "C" void kernel_launch(void* const* d_in, const int* in_sizes, int n_in,
                              void* d_out, int out_size, void* d_ws, size_t ws_size,
                              hipStream_t stream){
  const int* locations   = (const int*)d_in[0];
  const int* users       = (const int*)d_in[1];
  const int* weekdays    = (const int*)d_in[2];
  const int* start_mins  = (const int*)d_in[3];
  const void* mask       = d_in[4];
  const float* loc_table = (const float*)d_in[5];
  const float* user_table= (const float*)d_in[6];
  const float* hour_table= (const float*)d_in[7];
  const float* wd_table  = (const float*)d_in[8];
  const float* W_ih      = (const float*)d_in[9];
  const float* W_hh      = (const float*)d_in[10];
  const float* b_ih      = (const float*)d_in[11];
  const float* b_hh      = (const float*)d_in[12];
  const float* sc_W1     = (const float*)d_in[13];
  const float* sc_b1     = (const float*)d_in[14];
  const float* sc_W2     = (const float*)d_in[15];
  const float* sc_b2     = (const float*)d_in[16];
  const float* np_W1     = (const float*)d_in[17];
  const float* np_b1     = (const float*)d_in[18];
  const float* np_W2     = (const float*)d_in[19];
  const float* np_b2     = (const float*)d_in[20];
  const float* mx_W      = (const float*)d_in[21];
  const float* mx_b      = (const float*)d_in[22];
  float* out = (float*)d_out;

  char* w = (char*)d_ws;
  size_t o = 0;
  auto alloc = [&](size_t bytes)->void*{ void* p = w + o; o += (bytes + 255) & ~(size_t)255; return p; };
  float* X      = (float*)alloc((size_t)B_*S_*KX*sizeof(float));   // 235 MB
  float* Wc     = (float*)alloc((size_t)G4*KC*sizeof(float));      // 2.9 MB
  float* btot   = (float*)alloc((size_t)G4*sizeof(float));
  float* h0b    = (float*)alloc((size_t)B_*D_*sizeof(float));
  float* h1b    = (float*)alloc((size_t)B_*D_*sizeof(float));
  float* cbuf   = (float*)alloc((size_t)B_*D_*sizeof(float));
  float* ctx    = (float*)alloc((size_t)B_*D_*sizeof(float));
  float* newhid = (float*)alloc((size_t)B_*D_*sizeof(float));
  float* mixv   = (float*)alloc((size_t)B_*sizeof(float));
  float* scores = (float*)alloc((size_t)B_*5*sizeof(float));
  int*   slens  = (int*)alloc((size_t)B_*sizeof(int));
  int*   rlocs  = (int*)alloc((size_t)B_*5*sizeof(int));
  int*   keep   = (int*)alloc((size_t)B_*5*sizeof(int));
  int*   flag   = (int*)alloc(sizeof(int));

  k_init<<<512, 256, 0, stream>>>(h0b, cbuf, flag);
  k_detect<<<512, 256, 0, stream>>>((const unsigned char*)mask, flag);
  k_seqlen<<<2, 256, 0, stream>>>(mask, flag, slens);
  k_buildx<<<57344, 256, 0, stream>>>(locations, users, weekdays, start_mins,
                                      loc_table, user_table, hour_table, wd_table, X);
  k_buildw<<<2816, 256, 0, stream>>>(W_ih, W_hh, b_ih, b_hh, Wc, btot);
  for (int t=0; t<S_; t++){
    float* hin  = (t & 1) ? h1b : h0b;
    float* hout = (t & 1) ? h0b : h1b;
    k_lstm<<<dim3(32,8), 256, 0, stream>>>(t, X, Wc, btot, hin, hout, cbuf, ctx, slens);
  }
  k_post1<<<512, 256, 0, stream>>>(ctx, np_W1, np_b1, mx_W, mx_b, newhid, mixv);
  k_recent<<<512, 128, 0, stream>>>(locations, start_mins, slens, loc_table,
                                    sc_W1, sc_b1, sc_W2, sc_b2, scores, rlocs, keep);
  k_final<<<dim3(782,32), 256, 0, stream>>>(newhid, np_W2, np_b2, mixv, out);
  k_scatter<<<512, 64, 0, stream>>>(newhid, np_W2, np_b2, mixv, scores, rlocs, keep, out);
}

// Round 2
// 3579.539 us; speedup vs baseline: 3.0286x; 3.0286x over previous
//
#include <hip/hip_runtime.h>
#include <hip/hip_bf16.h>
#include <math.h>

#define B_ 512
#define S_ 256
#define D_ 256
#define NLOC 50000
#define KX 448      // D + TEMP
#define G4 1024
#define NEGV -1000000000.0f

typedef __attribute__((ext_vector_type(8))) short short8;
typedef __attribute__((ext_vector_type(4))) float f32x4;

__device__ __forceinline__ float sigmoidf_(float x){ return 1.0f/(1.0f+expf(-x)); }
__device__ __forceinline__ float geluf_(float x){ return 0.5f*x*(1.0f+erff(x*0.70710678118654752f)); }
__device__ __forceinline__ unsigned short f2bf_(float x){
  __hip_bfloat16 h = __float2bfloat16(x);
  return *(unsigned short*)&h;
}
__device__ __forceinline__ float bf2f_(unsigned short u){
  __hip_bfloat16 h = *(__hip_bfloat16*)&u;
  return __bfloat162float(h);
}

// ---- init: zero hbf0 (bf16), c (fp32), flag ----
__global__ void k_init(unsigned short* hbf, float* c, int* flag){
  int i = blockIdx.x*256 + threadIdx.x;
  if (i < B_*D_){ hbf[i]=0; c[i]=0.f; }
  if (i==0) *flag = 0;
}

// ---- detect mask layout: any nonzero odd byte in first B*S bytes => uint8 ----
__global__ void k_detect(const unsigned char* m, int* flag){
  int i = blockIdx.x*256 + threadIdx.x;
  if ((i & 1) && i < B_*S_ && m[i]) atomicOr(flag, 1);
}

// ---- seq_lens[b] = count(mask row) - 1 ----
__global__ void k_seqlen(const void* mp, const int* flag, int* slens){
  int b = blockIdx.x*256 + threadIdx.x;
  if (b >= B_) return;
  int cnt = 0;
  if (*flag){
    const unsigned char* m = (const unsigned char*)mp;
    for (int s=0;s<S_;s++) cnt += (m[b*S_+s] != 0);
  } else {
    const int* m = (const int*)mp;
    for (int s=0;s<S_;s++) cnt += (m[b*S_+s] != 0);
  }
  slens[b] = cnt - 1;
}

// ---- convert W_ih, W_hh to bf16; btot = b_ih + b_hh ----
__global__ void k_buildw(const float* wih, const float* whh, const float* bih,
                         const float* bhh, unsigned short* Wihbf,
                         unsigned short* Whhbf, float* btot){
  int i = blockIdx.x*256 + threadIdx.x;
  if (i < G4*KX) Wihbf[i] = f2bf_(wih[i]);
  if (i < G4*D_) Whhbf[i] = f2bf_(whh[i]);
  if (i < G4) btot[i] = bih[i] + bhh[i];
}

// ---- Gx = X @ W_ih^T + btot  (131072 x 1024, K=448), bf16 MFMA ----
// X gathered on the fly from embedding tables (never materialized).
// grid (8, 1024): x = N-tile (128 cols), y = M-tile (128 rows). 256 thr = 4 waves.
__global__ __launch_bounds__(256) void k_gx(
    const int* __restrict__ loc, const int* __restrict__ usr,
    const int* __restrict__ wdy, const int* __restrict__ sm,
    const float* __restrict__ loct, const float* __restrict__ usert,
    const float* __restrict__ hourt, const float* __restrict__ wdt,
    const unsigned short* __restrict__ Wihbf, const float* __restrict__ btot,
    unsigned short* __restrict__ Gx){
  __shared__ unsigned short As[128][40];   // row stride 40 (80B): 16B-aligned frags, 2-way-max banks
  int tid = threadIdx.x;
  int n0 = blockIdx.x*128, m0 = blockIdx.y*128;
  int w = tid>>6, lane = tid&63;
  int quad = lane>>4, l16 = lane&15;
  int mw = (w>>1)*64, nw = (w&1)*64;
  f32x4 acc[4][4] = {};                    // [mt][nt]
  int r0 = tid>>2, seg = tid&3;            // staging: rows r0, r0+64; cols seg*8..+8
  for (int kt=0; kt<14; kt++){
    int k0 = kt*32;
    int kc = k0 + seg*8;
    #pragma unroll
    for (int rr=0; rr<2; rr++){
      int r = r0 + rr*64;
      int row = m0 + r;                    // global row = b*S + t
      const float* src;
      if (kc < 256)      src = loct  + (size_t)loc[row]*256 + kc;
      else if (kc < 320) src = usert + (size_t)usr[row]*64 + (kc-256);
      else if (kc < 384) { int s = sm[row]; int hh = s/60; if (hh>24) hh=24; if (hh<0) hh=0;
                           src = hourt + (size_t)hh*64 + (kc-320); }
      else               src = wdt   + (size_t)wdy[row]*64 + (kc-384);
      float4 v0 = *(const float4*)(src);
      float4 v1 = *(const float4*)(src+4);
      short8 pk;
      pk[0]=f2bf_(v0.x); pk[1]=f2bf_(v0.y); pk[2]=f2bf_(v0.z); pk[3]=f2bf_(v0.w);
      pk[4]=f2bf_(v1.x); pk[5]=f2bf_(v1.y); pk[6]=f2bf_(v1.z); pk[7]=f2bf_(v1.w);
      *(short8*)&As[r][seg*8] = pk;
    }
    __syncthreads();
    short8 bfrag[4], afrag[4];
    #pragma unroll
    for (int nt=0; nt<4; nt++)
      bfrag[nt] = *(const short8*)(Wihbf + (size_t)(n0+nw+nt*16+l16)*KX + k0 + quad*8);
    #pragma unroll
    for (int mt=0; mt<4; mt++)
      afrag[mt] = *(const short8*)&As[mw+mt*16+l16][quad*8];
    #pragma unroll
    for (int mt=0; mt<4; mt++)
      #pragma unroll
      for (int nt=0; nt<4; nt++)
        acc[mt][nt] = __builtin_amdgcn_mfma_f32_16x16x32_bf16(afrag[mt], bfrag[nt], acc[mt][nt], 0, 0, 0);
    __syncthreads();
  }
  #pragma unroll
  for (int nt=0; nt<4; nt++){
    int col = n0 + nw + nt*16 + l16;
    float bv = btot[col];
    #pragma unroll
    for (int mt=0; mt<4; mt++){
      #pragma unroll
      for (int i=0; i<4; i++){
        int row = m0 + mw + mt*16 + quad*4 + i;
        Gx[(size_t)row*G4 + col] = f2bf_(acc[mt][nt][i] + bv);
      }
    }
  }
}

// ---- one LSTM step: g = h @ W_hh^T (bf16 MFMA) + Gx[:,t]; fused cell update ----
// grid (32, 4) x 256 thr: bx = batch tile (16 rows), (by*4+wave) = hidden d-tile (16 dims).
// Wave computes all 4 gates for its (16 batch x 16 d) patch.
__global__ __launch_bounds__(256) void k_step(int t,
    const unsigned short* __restrict__ Gx, const unsigned short* __restrict__ Whhbf,
    const unsigned short* __restrict__ hin, unsigned short* __restrict__ hout,
    float* __restrict__ c, float* __restrict__ ctx, const int* __restrict__ slens){
  int tid = threadIdx.x;
  int w = tid>>6, lane = tid&63;
  int quad = lane>>4, l16 = lane&15;
  int m0 = blockIdx.x*16;
  int d0 = (blockIdx.y*4 + w)*16;
  f32x4 acc[4] = {};
  #pragma unroll
  for (int kt=0; kt<8; kt++){
    int k0 = kt*32;
    short8 af = *(const short8*)(hin + (size_t)(m0+l16)*D_ + k0 + quad*8);
    #pragma unroll
    for (int q=0; q<4; q++){
      short8 bf = *(const short8*)(Whhbf + (size_t)(q*D_ + d0 + l16)*D_ + k0 + quad*8);
      acc[q] = __builtin_amdgcn_mfma_f32_16x16x32_bf16(af, bf, acc[q], 0, 0, 0);
    }
  }
  int d = d0 + l16;
  #pragma unroll
  for (int i=0; i<4; i++){
    int b = m0 + quad*4 + i;
    size_t gbase = ((size_t)b*S_ + t)*G4;
    float gi = acc[0][i] + bf2f_(Gx[gbase + d]);
    float gf = acc[1][i] + bf2f_(Gx[gbase + 256 + d]);
    float gg = acc[2][i] + bf2f_(Gx[gbase + 512 + d]);
    float go = acc[3][i] + bf2f_(Gx[gbase + 768 + d]);
    size_t ci = (size_t)b*D_ + d;
    float cold = c[ci];
    float cn = sigmoidf_(gf)*cold + sigmoidf_(gi)*tanhf(gg);
    float hn = sigmoidf_(go)*tanhf(cn);
    c[ci] = cn;
    hout[ci] = f2bf_(hn);
    if (t == slens[b]) ctx[ci] = hn;
  }
}

// ---- newhid = gelu(ctx @ np_W1^T + np_b1); mix = sigmoid(ctx . mx_W + mx_b)*0.9+0.05 ----
__global__ void k_post1(const float* __restrict__ ctx, const float* __restrict__ W1,
                        const float* __restrict__ b1, const float* __restrict__ mxW,
                        const float* __restrict__ mxb, float* newhid, float* mixv){
  __shared__ float cs[256];
  __shared__ float red[256];
  int b = blockIdx.x, tid = threadIdx.x;
  cs[tid] = ctx[(size_t)b*D_ + tid];
  __syncthreads();
  float a = b1[tid];
  const float* wr = W1 + (size_t)tid*D_;
  for (int k=0; k<D_; k++) a += cs[k]*wr[k];
  newhid[(size_t)b*D_ + tid] = geluf_(a);
  red[tid] = cs[tid]*mxW[tid];
  __syncthreads();
  for (int s=128; s>0; s>>=1){ if (tid<s) red[tid]+=red[tid+s]; __syncthreads(); }
  if (tid==0) mixv[b] = sigmoidf_(red[0]+mxb[0])*0.9f + 0.05f;
}

// ---- recent-location scores + dedup/keep ----
__global__ void k_recent(const int* __restrict__ loc, const int* __restrict__ sm,
                         const int* __restrict__ slens, const float* __restrict__ loct,
                         const float* __restrict__ W1, const float* __restrict__ b1,
                         const float* __restrict__ W2, const float* __restrict__ b2,
                         float* scores, int* rlocs, int* keep){
  __shared__ int rl[5], vs[5];
  __shared__ float td[5];
  __shared__ float red[128];
  int b = blockIdx.x, tid = threadIdx.x;
  int sl = slens[b];
  if (tid < 5){
    int idx = sl - tid;
    int v = idx >= 0;
    int ic = v ? idx : 0;
    rl[tid] = loc[b*S_ + ic];
    vs[tid] = v;
    int cur = sm[b*S_ + sl];
    td[tid] = (float)(cur - sm[b*S_ + ic]) * (1.0f/1440.0f);
  }
  __syncthreads();
  for (int j=0; j<5; j++){
    const float* lrow = loct + (size_t)rl[j]*D_;
    const float* wr = W1 + (size_t)tid*258;
    float a = b1[tid];
    for (int k=0; k<D_; k++) a += lrow[k]*wr[k];
    a += td[j]*wr[256] + (float)j*wr[257];
    red[tid] = geluf_(a)*W2[tid];
    __syncthreads();
    for (int s=64; s>0; s>>=1){ if (tid<s) red[tid]+=red[tid+s]; __syncthreads(); }
    if (tid==0) scores[b*5+j] = red[0] + b2[0];
    __syncthreads();
  }
  if (tid==0){
    for (int j=0; j<5; j++){
      int dup = 0;
      for (int k=0; k<j; k++) dup |= (rl[j]==rl[k]) && vs[k];
      keep[b*5+j] = vs[j] && !dup;
      rlocs[b*5+j] = rl[j];
    }
  }
}

// ---- big fused head: out[b,l] = mix*NEG + (1-mix)*(newhid[b].np_W2[l] + np_b2[l]) ----
__global__ __launch_bounds__(256) void k_final(const float* __restrict__ newhid,
    const float* __restrict__ W2, const float* __restrict__ b2,
    const float* __restrict__ mixv, float* __restrict__ out){
  __shared__ float Hs[16][256];
  __shared__ float Wl[64][65];
  int tid = threadIdx.x;
  int l0 = blockIdx.x*64, b0 = blockIdx.y*16;
  int ll = tid & 63, bq = tid >> 6;
  #pragma unroll
  for (int r=0; r<16; r++) Hs[r][tid] = newhid[(size_t)(b0+r)*D_ + tid];
  float acc[4] = {0.f,0.f,0.f,0.f};
  for (int kt=0; kt<4; kt++){
    int k0 = kt*64;
    __syncthreads();
    #pragma unroll
    for (int r=0; r<4; r++){
      int row = 4*r + bq;
      int l = l0 + row;
      Wl[row][ll] = (l < NLOC) ? W2[(size_t)l*D_ + k0 + ll] : 0.f;
    }
    __syncthreads();
    #pragma unroll
    for (int kk=0; kk<64; kk++){
      float wv = Wl[ll][kk];
      #pragma unroll
      for (int bi=0; bi<4; bi++) acc[bi] += wv * Hs[bq*4+bi][k0+kk];
    }
  }
  int l = l0 + ll;
  if (l < NLOC){
    float bias = b2[l];
    #pragma unroll
    for (int bi=0; bi<4; bi++){
      int b = b0 + bq*4 + bi;
      float mx = mixv[b];
      out[(size_t)b*NLOC + l] = mx*NEGV + (1.0f-mx)*(acc[bi] + bias);
    }
  }
}

// ---- overwrite kept recent locations ----
__global__ void k_scatter(const float* __restrict__ newhid, const float* __restrict__ W2,
                          const float* __restrict__ b2, const float* __restrict__ mixv,
                          const float* __restrict__ scores, const int* __restrict__ rlocs,
                          const int* __restrict__ keep, float* out){
  int b = blockIdx.x, lane = threadIdx.x;
  float mx = mixv[b];
  for (int j=0; j<5; j++){
    if (!keep[b*5+j]) continue;
    int rl = rlocs[b*5+j];
    const float* wr = W2 + (size_t)rl*D_;
    const float* hr = newhid + (size_t)b*D_;
    float a = 0.f;
    #pragma unroll
    for (int q=0; q<4; q++){ int k = lane + 64*q; a += hr[k]*wr[k]; }
    #pragma unroll
    for (int off=32; off>0; off>>=1) a += __shfl_xor(a, off, 64);
    if (lane==0)
      out[(size_t)b*NLOC + rl] = mx*scores[b*5+j] + (1.0f-mx)*(a + b2[rl]);
  }
}

extern "C" void kernel_launch(void* const* d_in, const int* in_sizes, int n_in,
                              void* d_out, int out_size, void* d_ws, size_t ws_size,
                              hipStream_t stream){
  const int* locations   = (const int*)d_in[0];
  const int* users       = (const int*)d_in[1];
  const int* weekdays    = (const int*)d_in[2];
  const int* start_mins  = (const int*)d_in[3];
  const void* mask       = d_in[4];
  const float* loc_table = (const float*)d_in[5];
  const float* user_table= (const float*)d_in[6];
  const float* hour_table= (const float*)d_in[7];
  const float* wd_table  = (const float*)d_in[8];
  const float* W_ih      = (const float*)d_in[9];
  const float* W_hh      = (const float*)d_in[10];
  const float* b_ih      = (const float*)d_in[11];
  const float* b_hh      = (const float*)d_in[12];
  const float* sc_W1     = (const float*)d_in[13];
  const float* sc_b1     = (const float*)d_in[14];
  const float* sc_W2     = (const float*)d_in[15];
  const float* sc_b2     = (const float*)d_in[16];
  const float* np_W1     = (const float*)d_in[17];
  const float* np_b1     = (const float*)d_in[18];
  const float* np_W2     = (const float*)d_in[19];
  const float* np_b2     = (const float*)d_in[20];
  const float* mx_W      = (const float*)d_in[21];
  const float* mx_b      = (const float*)d_in[22];
  float* out = (float*)d_out;

  char* w = (char*)d_ws;
  size_t o = 0;
  auto alloc = [&](size_t bytes)->void*{ void* p = w + o; o += (bytes + 255) & ~(size_t)255; return p; };
  unsigned short* Gx    = (unsigned short*)alloc((size_t)B_*S_*G4*sizeof(short)); // 268 MB bf16
  unsigned short* Wihbf = (unsigned short*)alloc((size_t)G4*KX*sizeof(short));
  unsigned short* Whhbf = (unsigned short*)alloc((size_t)G4*D_*sizeof(short));
  float* btot   = (float*)alloc((size_t)G4*sizeof(float));
  unsigned short* hbf0 = (unsigned short*)alloc((size_t)B_*D_*sizeof(short));
  unsigned short* hbf1 = (unsigned short*)alloc((size_t)B_*D_*sizeof(short));
  float* cbuf   = (float*)alloc((size_t)B_*D_*sizeof(float));
  float* ctx    = (float*)alloc((size_t)B_*D_*sizeof(float));
  float* newhid = (float*)alloc((size_t)B_*D_*sizeof(float));
  float* mixv   = (float*)alloc((size_t)B_*sizeof(float));
  float* scores = (float*)alloc((size_t)B_*5*sizeof(float));
  int*   slens  = (int*)alloc((size_t)B_*sizeof(int));
  int*   rlocs  = (int*)alloc((size_t)B_*5*sizeof(int));
  int*   keep   = (int*)alloc((size_t)B_*5*sizeof(int));
  int*   flag   = (int*)alloc(sizeof(int));

  k_init<<<512, 256, 0, stream>>>(hbf0, cbuf, flag);
  k_detect<<<512, 256, 0, stream>>>((const unsigned char*)mask, flag);
  k_seqlen<<<2, 256, 0, stream>>>(mask, flag, slens);
  k_buildw<<<1792, 256, 0, stream>>>(W_ih, W_hh, b_ih, b_hh, Wihbf, Whhbf, btot);
  k_gx<<<dim3(8,1024), 256, 0, stream>>>(locations, users, weekdays, start_mins,
                                         loc_table, user_table, hour_table, wd_table,
                                         Wihbf, btot, Gx);
  for (int t=0; t<S_; t++){
    unsigned short* hin  = (t & 1) ? hbf1 : hbf0;
    unsigned short* hout = (t & 1) ? hbf0 : hbf1;
    k_step<<<dim3(32,4), 256, 0, stream>>>(t, Gx, Whhbf, hin, hout, cbuf, ctx, slens);
  }
  k_post1<<<512, 256, 0, stream>>>(ctx, np_W1, np_b1, mx_W, mx_b, newhid, mixv);
  k_recent<<<512, 128, 0, stream>>>(locations, start_mins, slens, loc_table,
                                    sc_W1, sc_b1, sc_W2, sc_b2, scores, rlocs, keep);
  k_final<<<dim3(782,32), 256, 0, stream>>>(newhid, np_W2, np_b2, mixv, out);
  k_scatter<<<512, 64, 0, stream>>>(newhid, np_W2, np_b2, mixv, scores, rlocs, keep, out);
}